// Round 2
// baseline (150.805 us; speedup 1.0000x reference)
//
#include <hip/hip_runtime.h>
#include <hip/hip_bf16.h>

typedef __attribute__((ext_vector_type(8))) short short8v;   // 8 bf16 (4 VGPRs)
typedef __attribute__((ext_vector_type(4))) float f32x4;
typedef __attribute__((ext_vector_type(16))) float f32x16;
typedef unsigned short u16;
typedef unsigned int u32;

#define MFMA16x16x32(a, b, c) __builtin_amdgcn_mfma_f32_16x16x32_bf16((a), (b), (c), 0, 0, 0)
#define MFMA32(a, b, c) __builtin_amdgcn_mfma_f32_32x32x16_bf16((a), (b), (c), 0, 0, 0)

#define SL2E 0.16128870444460512f   // (1/sqrt(80)) * log2(e)

__device__ inline u16 f2bf(float f) {
  __hip_bfloat16 h = __float2bfloat16(f);
  return *reinterpret_cast<u16*>(&h);
}
__device__ inline float bf2f(u16 u) {
  __hip_bfloat16 h;
  *reinterpret_cast<u16*>(&h) = u;
  return __bfloat162float(h);
}

// async 16B global->LDS; LDS dest is wave-uniform base + lane*16
__device__ inline void gld_lds16(const u16* g, u16* l) {
  __builtin_amdgcn_global_load_lds(
      (const __attribute__((address_space(1))) u32*)g,
      (__attribute__((address_space(3))) u32*)l, 16, 0, 0);
}

// ---------------- fused fp32 -> bf16 convert (hidden + qkv_w + proj_w) ----------------
__global__ __launch_bounds__(256) void cvt_all(const float* __restrict__ h,
                                               const float* __restrict__ qw,
                                               const float* __restrict__ pw,
                                               u16* __restrict__ dh,
                                               u16* __restrict__ dqw,
                                               u16* __restrict__ dpw) {
  const int N1 = 1310720;            // 4096*1280/4
  const int N2 = 1228800;            // 3840*1280/4
  const int N3 = 409600;             // 1280*1280/4
  for (int c = blockIdx.x * 256 + threadIdx.x; c < N1 + N2 + N3;
       c += gridDim.x * 256) {
    const float* s;
    u16* d;
    int i;
    if (c < N1) { s = h; d = dh; i = c * 4; }
    else if (c < N1 + N2) { s = qw; d = dqw; i = (c - N1) * 4; }
    else { s = pw; d = dpw; i = (c - N1 - N2) * 4; }
    float4 v = *(const float4*)&s[i];
    u32 lo = (u32)f2bf(v.x) | ((u32)f2bf(v.y) << 16);
    u32 hi = (u32)f2bf(v.z) | ((u32)f2bf(v.w) << 16);
    uint2 o; o.x = lo; o.y = hi;
    *(uint2*)&d[i] = o;
  }
}

// ---------------- RoPE, vectorized 8-wide: one thread per (tok, head, chunk-pair) ----------------
__global__ __launch_bounds__(256) void rope2_k(u16* __restrict__ qbuf,
                                               u16* __restrict__ kc,
                                               const float* __restrict__ rot) {
  int t = blockIdx.x * 256 + threadIdx.x;     // 4096*16*5 = 327680 threads
  int s = t / 80, rem = t % 80;
  int h = rem / 5, dc = rem % 5;
  const float* rp = &rot[s * 40 + dc * 8];
  float c[8], sn[8];
#pragma unroll
  for (int j = 0; j < 8; ++j) __sincosf(rp[j], &sn[j], &c[j]);
  {  // Q (prescaled by SL2E in epilogue; rotation commutes with scaling)
    u16* q1 = &qbuf[(size_t)s * 1280 + h * 80 + dc * 8];
    uint4 a = *(uint4*)q1, b = *(uint4*)(q1 + 40);
    const u16* pa = (const u16*)&a;
    const u16* pb = (const u16*)&b;
    alignas(16) u16 oa[8], ob[8];
#pragma unroll
    for (int j = 0; j < 8; ++j) {
      float x1 = bf2f(pa[j]), x2 = bf2f(pb[j]);
      oa[j] = f2bf(x1 * c[j] - x2 * sn[j]);
      ob[j] = f2bf(x2 * c[j] + x1 * sn[j]);
    }
    *(uint4*)q1 = *(uint4*)oa;
    *(uint4*)(q1 + 40) = *(uint4*)ob;
  }
  {  // K in kc chunk layout
    u16* k1 = &kc[((size_t)(h * 10 + dc) * 4096 + (size_t)s) * 8];
    u16* k2 = &kc[((size_t)(h * 10 + dc + 5) * 4096 + (size_t)s) * 8];
    uint4 a = *(uint4*)k1, b = *(uint4*)k2;
    const u16* pa = (const u16*)&a;
    const u16* pb = (const u16*)&b;
    alignas(16) u16 oa[8], ob[8];
#pragma unroll
    for (int j = 0; j < 8; ++j) {
      float x1 = bf2f(pa[j]), x2 = bf2f(pb[j]);
      oa[j] = f2bf(x1 * c[j] - x2 * sn[j]);
      ob[j] = f2bf(x2 * c[j] + x1 * sn[j]);
    }
    *(uint4*)k1 = *(uint4*)oa;
    *(uint4*)k2 = *(uint4*)ob;
  }
}

// ======== QKV GEMM (R13): 128^2 tile, 4 waves, ring-3, 960 blocks -> 3 blocks/CU ========
// Rationale: R11's 256^2/128KiB-LDS ran 1 block/CU (240 blocks) -> every barrier fully
// drains the CU; R12 (phase-split) showed more barriers = worse at 1 block/CU. This uses
// the proven gemm4r datapath (same swizzle/counted-vmcnt) at 48 KiB LDS so 3 desync'd
// blocks/CU hide each other's barrier+vmcnt stalls. Split q/k/v epilogue ported to the
// 4-wave geometry (region boundaries 1280/2560 are multiples of 128 -> uniform branch).
__global__ __launch_bounds__(256, 3) void gemm_qkv(const u16* __restrict__ A,
                                                   const u16* __restrict__ B,
                                                   const float* __restrict__ bias,
                                                   u16* __restrict__ qbuf,
                                                   u16* __restrict__ kc,
                                                   u16* __restrict__ vtb,
                                                   int M, int N, int K) {
  __shared__ u16 lds_[24576];              // A ring [3][128][32] | B ring [3][128][32]
  u16* ringA = lds_;
  u16* ringB = lds_ + 12288;
  const int tid = threadIdx.x, lane = tid & 63, w = tid >> 6;
  const int lr = lane & 15, lq = lane >> 4;
  const int wr = w >> 1, wc = w & 1;
  const int per = gridDim.x >> 3;
  const int flat = blockIdx.x;
  const int f2 = (flat & 7) * per + (flat >> 3);
  const int nbn = N >> 7;                  // 30
  const int m0 = (f2 / nbn) << 7, n0 = (f2 % nbn) << 7;
  const int NT = K >> 5;                   // 40

#define STAGE_Q(t_, ring_, src0_)                                          \
  do {                                                                     \
    int tt = (t_);                                                         \
    u16* dst = (ring_) + (tt % 3) * 4096 + w * 512;                        \
    const u16* src = (src0_) + tt * 32;                                    \
    _Pragma("unroll") for (int l = 0; l < 2; ++l) {                        \
      int q = l * 256 + tid;                                               \
      int row = q >> 2, sl = (q & 3) ^ ((row >> 1) & 3);                   \
      gld_lds16(&src[(size_t)row * K + sl * 8], dst + l * 2048);           \
    }                                                                      \
  } while (0)

  const u16* A0 = A + (size_t)m0 * K;
  const u16* B0 = B + (size_t)n0 * K;

  f32x4 acc[4][4] = {};

  STAGE_Q(0, ringA, A0); STAGE_Q(0, ringB, B0);
  if (NT > 1) { STAGE_Q(1, ringA, A0); STAGE_Q(1, ringB, B0); }
  if (NT > 1) asm volatile("s_waitcnt vmcnt(4)" ::: "memory");
  else        asm volatile("s_waitcnt vmcnt(0)" ::: "memory");
  __builtin_amdgcn_s_barrier();
  __builtin_amdgcn_sched_barrier(0);

  short8v af[4], bf[4];
  for (int t = 0; t < NT; ++t) {
    const u16* As = ringA + (t % 3) * 4096;
    const u16* Bs = ringB + (t % 3) * 4096;
#pragma unroll
    for (int i = 0; i < 4; ++i) {
      int row = wr * 64 + i * 16 + lr;
      af[i] = *(const short8v*)&As[row * 32 + ((lq ^ ((row >> 1) & 3)) << 3)];
    }
#pragma unroll
    for (int j = 0; j < 4; ++j) {
      int row = wc * 64 + j * 16 + lr;
      bf[j] = *(const short8v*)&Bs[row * 32 + ((lq ^ ((row >> 1) & 3)) << 3)];
    }
    if (t + 2 < NT) { STAGE_Q(t + 2, ringA, A0); STAGE_Q(t + 2, ringB, B0); }
    __builtin_amdgcn_sched_barrier(0);
    // gate: tile t+1 fully landed (its 4 ops are the oldest outstanding)
    if (t + 2 < NT) asm volatile("s_waitcnt vmcnt(4)" ::: "memory");
    else            asm volatile("s_waitcnt vmcnt(0)" ::: "memory");
    __builtin_amdgcn_s_barrier();
    __builtin_amdgcn_sched_barrier(0);
    __builtin_amdgcn_s_setprio(1);
#pragma unroll
    for (int i = 0; i < 4; ++i)
#pragma unroll
      for (int j = 0; j < 4; ++j)
        acc[i][j] = MFMA16x16x32(af[i], bf[j], acc[i][j]);
    __builtin_amdgcn_s_setprio(0);
  }
#undef STAGE_Q

  // ---- split epilogue: q (prescaled) / k (kc layout) / v (transposed) ----
#pragma unroll
  for (int j = 0; j < 4; ++j) {
    int gn = n0 + wc * 64 + j * 16 + lr;
    float bv = bias[gn];
    if (gn < 1280) {
#pragma unroll
      for (int i = 0; i < 4; ++i)
#pragma unroll
        for (int r = 0; r < 4; ++r) {
          int gm = m0 + wr * 64 + i * 16 + lq * 4 + r;
          qbuf[(size_t)gm * 1280 + gn] = f2bf((acc[i][j][r] + bv) * SL2E);
        }
    } else if (gn < 2560) {
      int wi = gn - 1280, h = wi / 80, d = wi % 80;
      u16* base = kc + ((size_t)(h * 10 + (d >> 3)) * 4096) * 8 + (d & 7);
#pragma unroll
      for (int i = 0; i < 4; ++i)
#pragma unroll
        for (int r = 0; r < 4; ++r) {
          int gm = m0 + wr * 64 + i * 16 + lq * 4 + r;
          base[(size_t)gm * 8] = f2bf(acc[i][j][r] + bv);
        }
    } else {
      int wi = gn - 2560, h = wi / 80, d = wi % 80;
      u16* vrow = vtb + (size_t)(h * 80 + d) * 4096;
#pragma unroll
      for (int i = 0; i < 4; ++i) {
        int gm0 = m0 + wr * 64 + i * 16 + lq * 4;
        alignas(8) u16 t4[4];
#pragma unroll
        for (int r = 0; r < 4; ++r) t4[r] = f2bf(acc[i][j][r] + bv);
        *(uint2*)&vrow[gm0] = *(const uint2*)t4;
      }
    }
  }
}

// ======== proj GEMM: 128^2 tile, 4 waves, ring-4 counted-vmcnt ========
__global__ __launch_bounds__(256) void gemm4r(const u16* __restrict__ A,
                                              const u16* __restrict__ B,
                                              const float* __restrict__ bias,
                                              float* __restrict__ Cout,
                                              int M, int N, int K) {
  __shared__ u16 lds_[32768];              // A ring [4][128][32] | B ring [4][128][32]
  u16* ringA = lds_;
  u16* ringB = lds_ + 16384;
  const int tid = threadIdx.x, lane = tid & 63, w = tid >> 6;
  const int lr = lane & 15, lq = lane >> 4;
  const int wr = w >> 1, wc = w & 1;
  const int nwg = gridDim.x;
  const int per = nwg >> 3;
  const int flat = blockIdx.x;
  const int f2 = (flat & 7) * per + (flat >> 3);
  const int nbn = N >> 7;
  const int m0 = (f2 / nbn) << 7, n0 = (f2 % nbn) << 7;
  const int NT = K >> 5;

#define STAGE_P(t_, ring_, src0_)                                          \
  do {                                                                     \
    int tt = (t_);                                                         \
    u16* dst = (ring_) + (tt & 3) * 4096 + w * 512;                        \
    const u16* src = (src0_) + tt * 32;                                    \
    _Pragma("unroll") for (int l = 0; l < 2; ++l) {                        \
      int q = l * 256 + tid;                                               \
      int row = q >> 2, sl = (q & 3) ^ ((row >> 1) & 3);                   \
      gld_lds16(&src[(size_t)row * K + sl * 8], dst + l * 2048);           \
    }                                                                      \
  } while (0)

  const u16* A0 = A + (size_t)m0 * K;
  const u16* B0 = B + (size_t)n0 * K;

  f32x4 acc[4][4] = {};

  STAGE_P(0, ringA, A0); STAGE_P(0, ringB, B0);
  if (NT > 1) { STAGE_P(1, ringA, A0); STAGE_P(1, ringB, B0); }
  if (NT > 2) { STAGE_P(2, ringA, A0); STAGE_P(2, ringB, B0); }
  if (NT > 2) asm volatile("s_waitcnt vmcnt(8)" ::: "memory");
  else        asm volatile("s_waitcnt vmcnt(0)" ::: "memory");
  __builtin_amdgcn_s_barrier();
  __builtin_amdgcn_sched_barrier(0);

  short8v af[4], bf[4];
  for (int t = 0; t < NT; ++t) {
    const u16* As = ringA + (t & 3) * 4096;
    const u16* Bs = ringB + (t & 3) * 4096;
#pragma unroll
    for (int i = 0; i < 4; ++i) {
      int row = wr * 64 + i * 16 + lr;
      af[i] = *(const short8v*)&As[row * 32 + ((lq ^ ((row >> 1) & 3)) << 3)];
    }
#pragma unroll
    for (int j = 0; j < 4; ++j) {
      int row = wc * 64 + j * 16 + lr;
      bf[j] = *(const short8v*)&Bs[row * 32 + ((lq ^ ((row >> 1) & 3)) << 3)];
    }
    if (t + 3 < NT) { STAGE_P(t + 3, ringA, A0); STAGE_P(t + 3, ringB, B0); }
    __builtin_amdgcn_sched_barrier(0);
    {
      int rem = NT - t - 2;
      if (rem >= 2)      asm volatile("s_waitcnt vmcnt(8)" ::: "memory");
      else if (rem == 1) asm volatile("s_waitcnt vmcnt(4)" ::: "memory");
      else               asm volatile("s_waitcnt vmcnt(0)" ::: "memory");
    }
    __builtin_amdgcn_s_barrier();
    __builtin_amdgcn_sched_barrier(0);
    __builtin_amdgcn_s_setprio(1);
#pragma unroll
    for (int i = 0; i < 4; ++i)
#pragma unroll
      for (int j = 0; j < 4; ++j)
        acc[i][j] = MFMA16x16x32(af[i], bf[j], acc[i][j]);
    __builtin_amdgcn_s_setprio(0);
  }
#undef STAGE_P

#pragma unroll
  for (int j = 0; j < 4; ++j) {
    int gn = n0 + wc * 64 + j * 16 + lr;
    float bv = bias[gn];
#pragma unroll
    for (int i = 0; i < 4; ++i) {
#pragma unroll
      for (int r = 0; r < 4; ++r) {
        int gm = m0 + wr * 64 + i * 16 + lq * 4 + r;
        Cout[(size_t)gm * N + gn] = acc[i][j][r] + bv;
      }
    }
  }
}

// ---------------- flash attention: 8 waves share each staged tile (256 q/block) ----------------
// grid (4,16,4) XCD-swizzled = 256 blocks, 512 thr; LDS 67.6KB -> 2 blocks/CU = 4 waves/SIMD.
// Per-wave datapath identical to R11 (32 q/wave, no extra registers). Staging split:
// waves 0-3 carry 3 loads/stage (K), waves 4-7 carry 2 (V) -> per-wave vmcnt(3)/vmcnt(2).
__global__ __launch_bounds__(512, 2) void attn_k(const u16* __restrict__ qbuf,
                                                 const u16* __restrict__ kc,
                                                 const u16* __restrict__ vtb,
                                                 u16* __restrict__ out,
                                                 const int* __restrict__ cu) {
  __shared__ u16 Kb[3][5120];    // [buf][dc 10][tok 64][8]
  __shared__ u16 Vb[3][6144];    // [buf][d 96][tokchunk 8][8]; row 80 = ones, 81..95 = 0
  const int tid = threadIdx.x, lane = tid & 63, w = tid >> 6;
  const int l31 = lane & 31, lh = lane >> 5;
  int flat = blockIdx.x + 4 * (blockIdx.y + 16 * blockIdx.z);
  int f2 = (flat & 7) * 32 + (flat >> 3);
  const int qt = f2 & 3, head = (f2 >> 2) & 15, seg = f2 >> 6;
  const int seg0 = cu[seg], qend = cu[seg + 1];
  const int q0 = seg0 + qt * 256;
  if (q0 >= qend) return;
  const int nkt = (qend - seg0 + 63) >> 6;

  // preset V pad rows 80..95 (row 80 = 1.0 for free rowsum), all 3 buffers
  for (int c = tid; c < 3072; c += 512) {
    int b = c >> 10, rc = c & 1023;
    Vb[b][5120 + rc] = (rc < 64) ? (u16)0x3F80 : (u16)0;
  }

  // ---- Q B-frags direct from qbuf (once; Q prescaled by SL2E) ----
  const int qtok = q0 + w * 32 + l31;
  const int qtokc = min(qtok, qend - 1);
  const u16* qb = qbuf + (size_t)qtokc * 1280 + head * 80 + lh * 8;
  short8v aq[5];
#pragma unroll
  for (int st = 0; st < 5; ++st) aq[st] = *(const short8v*)&qb[st * 16];

  const u16* kch = kc + (size_t)head * 10 * 4096 * 8;
  const u16* vth = vtb + (size_t)head * 80 * 4096;
  const int vrow = lane >> 3, vtc = (lane & 7) ^ (lane >> 3);

#define GLDK(i_, kb0_, buf_)                                                     \
  gld_lds16(&kch[((size_t)(i_) * 4096 + min((kb0_) + lane, 4095)) * 8],          \
            &Kb[buf_][(i_) * 512])
#define GLDV(i_, kb0_, buf_)                                                     \
  gld_lds16(&vth[(size_t)((i_) * 8 + vrow) * 4096 + min((kb0_) + vtc * 8, 4088)],\
            &Vb[buf_][(i_) * 512])
// waves 0-3: K{w, w+4} + (w<2 ? K{8+w} : V{6+w -> 8,9}); waves 4-7: V{w-4, w}
#define STAGE_KV(kt_, buf_)                                                      \
  do {                                                                           \
    int kb0_ = seg0 + (kt_) * 64;                                                \
    if (w < 4) {                                                                 \
      GLDK(w, kb0_, buf_);                                                       \
      GLDK(w + 4, kb0_, buf_);                                                   \
      if (w < 2) GLDK(8 + w, kb0_, buf_);                                        \
      else       GLDV(6 + w, kb0_, buf_);                                        \
    } else {                                                                     \
      GLDV(w - 4, kb0_, buf_);                                                   \
      GLDV(w, kb0_, buf_);                                                       \
    }                                                                            \
  } while (0)

  STAGE_KV(0, 0);
  if (nkt > 1) STAGE_KV(1, 1);
  __syncthreads();               // pad-init ds_writes visible to all waves

  f32x16 o_acc[3] = {};
  int cur = 0;
  for (int kt = 0; kt < nkt; ++kt) {
    const int valid = min(64, qend - (seg0 + kt * 64));
    if (kt + 1 < nkt) {
      if (w < 4) asm volatile("s_waitcnt vmcnt(3)" ::: "memory");
      else       asm volatile("s_waitcnt vmcnt(2)" ::: "memory");
    } else {
      asm volatile("s_waitcnt vmcnt(0)" ::: "memory");
    }
    __builtin_amdgcn_s_barrier();
    if (kt + 2 < nkt) {
      int ns = cur + 2; if (ns >= 3) ns -= 3;
      STAGE_KV(kt + 2, ns);
    }

    // ---- QK^T swapped: S^T[k][q] (Q prescaled -> p = exp2(sac)) ----
    f32x16 sac0 = {}, sac1 = {};
    const u16* kbp = &Kb[cur][l31 * 8];
    __builtin_amdgcn_s_setprio(1);
#pragma unroll
    for (int st = 0; st < 5; ++st) {
      int dc = st * 2 + lh;
      short8v kf0 = *(const short8v*)&kbp[dc * 512];
      short8v kf1 = *(const short8v*)&kbp[dc * 512 + 256];
      sac0 = MFMA32(kf0, aq[st], sac0);
      sac1 = MFMA32(kf1, aq[st], sac1);
    }
    __builtin_amdgcn_s_setprio(0);

    f32x16 p0, p1;
#pragma unroll
    for (int i = 0; i < 16; ++i) {
      p0[i] = exp2f(sac0[i]);
      p1[i] = exp2f(sac1[i]);
    }
    if (valid < 64) {
#pragma unroll
      for (int i = 0; i < 16; ++i) {
        int k0_ = (i & 3) + 8 * (i >> 2) + 4 * lh;
        if (k0_ >= valid) p0[i] = 0.f;
        if (32 + k0_ >= valid) p1[i] = 0.f;
      }
    }

    // ---- P -> PV B-frags via cvt_pk + permlane32_swap (no LDS) ----
    short8v pfrag[4];
#pragma unroll
    for (int st = 0; st < 4; ++st) {
      int s0 = 8 * (st & 1);
      u32 c0, c1, c2, c3;
      if (st < 2) {
        asm("v_cvt_pk_bf16_f32 %0, %1, %2" : "=v"(c0) : "v"(p0[s0 + 0]), "v"(p0[s0 + 1]));
        asm("v_cvt_pk_bf16_f32 %0, %1, %2" : "=v"(c1) : "v"(p0[s0 + 2]), "v"(p0[s0 + 3]));
        asm("v_cvt_pk_bf16_f32 %0, %1, %2" : "=v"(c2) : "v"(p0[s0 + 4]), "v"(p0[s0 + 5]));
        asm("v_cvt_pk_bf16_f32 %0, %1, %2" : "=v"(c3) : "v"(p0[s0 + 6]), "v"(p0[s0 + 7]));
      } else {
        asm("v_cvt_pk_bf16_f32 %0, %1, %2" : "=v"(c0) : "v"(p1[s0 + 0]), "v"(p1[s0 + 1]));
        asm("v_cvt_pk_bf16_f32 %0, %1, %2" : "=v"(c1) : "v"(p1[s0 + 2]), "v"(p1[s0 + 3]));
        asm("v_cvt_pk_bf16_f32 %0, %1, %2" : "=v"(c2) : "v"(p1[s0 + 4]), "v"(p1[s0 + 5]));
        asm("v_cvt_pk_bf16_f32 %0, %1, %2" : "=v"(c3) : "v"(p1[s0 + 6]), "v"(p1[s0 + 7]));
      }
      asm volatile("v_permlane32_swap_b32 %0, %1" : "+v"(c0), "+v"(c2));
      asm volatile("v_permlane32_swap_b32 %0, %1" : "+v"(c1), "+v"(c3));
      uint4 u = make_uint4(c0, c1, c2, c3);
      pfrag[st] = *reinterpret_cast<short8v*>(&u);
    }

    // ---- PV: O^T[d][q] += V * P (row 80 of V = ones -> rowsum in o_acc[2][8], lh=0) ----
    __builtin_amdgcn_s_setprio(1);
#pragma unroll
    for (int df = 0; df < 3; ++df) {
#pragma unroll
      for (int st2 = 0; st2 < 4; ++st2) {
        int tcp = (st2 * 2 + lh) ^ (l31 & 7);
        short8v vf = *(const short8v*)&Vb[cur][(df * 32 + l31) * 64 + tcp * 8];
        o_acc[df] = MFMA32(vf, pfrag[st2], o_acc[df]);
      }
    }
    __builtin_amdgcn_s_setprio(0);

    cur = (cur == 2) ? 0 : cur + 1;
  }
#undef STAGE_KV
#undef GLDK
#undef GLDV

  // ---- normalize + store (lh=1 partner's o_acc[2][8] is V-row 84 = 0, so sum is safe) ----
  float rs = o_acc[2][8];
  rs += __shfl_xor(rs, 32);
  float invq = 1.0f / rs;
  if (qtok < qend) {
#pragma unroll
    for (int df = 0; df < 3; ++df) {
#pragma unroll
      for (int i = 0; i < 16; ++i) {
        if (df == 2 && i >= 8) continue;
        int d = df * 32 + (i & 3) + 8 * (i >> 2) + 4 * lh;
        out[(size_t)qtok * 1280 + head * 80 + d] = f2bf(o_acc[df][i] * invq);
      }
    }
  }
}

// ---------------- host launch ----------------
extern "C" void kernel_launch(void* const* d_in, const int* in_sizes, int n_in,
                              void* d_out, int out_size, void* d_ws, size_t ws_size,
                              hipStream_t stream) {
  const float* hidden = (const float*)d_in[0];
  const float* rot    = (const float*)d_in[1];
  const float* qkv_w  = (const float*)d_in[2];
  const float* qkv_b  = (const float*)d_in[3];
  const float* proj_w = (const float*)d_in[4];
  const float* proj_b = (const float*)d_in[5];
  const int*   cu     = (const int*)d_in[6];
  float* out = (float*)d_out;

  char* ws = (char*)d_ws;
  u16* hid_bf   = (u16*)(ws);                    // 10,485,760
  u16* qkvw_bf  = (u16*)(ws + 10485760);         //  9,830,400
  u16* projw_bf = (u16*)(ws + 20316160);         //  3,276,800
  u16* qbuf     = (u16*)(ws + 23592960);         // 10,485,760
  u16* kc       = (u16*)(ws + 34078720);         // 10,485,760
  u16* vtb      = (u16*)(ws + 44564480);         // 10,485,760
  u16* attn_bf  = (u16*)(ws + 55050240);         // 10,485,760 -> total 65,536,000

  cvt_all<<<2048, 256, 0, stream>>>(hidden, qkv_w, proj_w, hid_bf, qkvw_bf, projw_bf);

  gemm_qkv<<<960, 256, 0, stream>>>(hid_bf, qkvw_bf, qkv_b, qbuf, kc, vtb,
                                    4096, 3840, 1280);
  rope2_k<<<1280, 256, 0, stream>>>(qbuf, kc, rot);
  attn_k<<<dim3(4, 16, 4), 512, 0, stream>>>(qbuf, kc, vtb, attn_bf, cu);
  gemm4r<<<320, 256, 0, stream>>>(attn_bf, projw_bf, proj_b, out, 4096, 1280, 1280);
}

// Round 3
// 118.417 us; speedup vs baseline: 1.2735x; 1.2735x over previous
//
#include <hip/hip_runtime.h>
#include <hip/hip_bf16.h>

typedef __attribute__((ext_vector_type(8))) short short8v;   // 8 bf16 (4 VGPRs)
typedef __attribute__((ext_vector_type(4))) float f32x4;
typedef __attribute__((ext_vector_type(16))) float f32x16;
typedef unsigned short u16;
typedef unsigned int u32;

#define MFMA16x16x32(a, b, c) __builtin_amdgcn_mfma_f32_16x16x32_bf16((a), (b), (c), 0, 0, 0)
#define MFMA32(a, b, c) __builtin_amdgcn_mfma_f32_32x32x16_bf16((a), (b), (c), 0, 0, 0)

#define SL2E 0.16128870444460512f   // (1/sqrt(80)) * log2(e)

__device__ inline u16 f2bf(float f) {
  __hip_bfloat16 h = __float2bfloat16(f);
  return *reinterpret_cast<u16*>(&h);
}
__device__ inline float bf2f(u16 u) {
  __hip_bfloat16 h;
  *reinterpret_cast<u16*>(&h) = u;
  return __bfloat162float(h);
}

// async 16B global->LDS; LDS dest is wave-uniform base + lane*16
__device__ inline void gld_lds16(const u16* g, u16* l) {
  __builtin_amdgcn_global_load_lds(
      (const __attribute__((address_space(1))) u32*)g,
      (__attribute__((address_space(3))) u32*)l, 16, 0, 0);
}

// ---------------- fused fp32 -> bf16 convert (hidden + qkv_w + proj_w) ----------------
// R15: qkv_w q/k output-dim rows are PERMUTED on store: within each head,
// orig dim d<40 -> 2d, d>=40 -> 2(d-40)+1. QK^T is invariant under a consistent
// permutation of head dims of Q and K, and it makes RoPE pairs ADJACENT columns
// so gemm_qkv's epilogue can rotate via __shfl_xor(.,1) (rope2_k kernel deleted).
__global__ __launch_bounds__(256) void cvt_all(const float* __restrict__ h,
                                               const float* __restrict__ qw,
                                               const float* __restrict__ pw,
                                               u16* __restrict__ dh,
                                               u16* __restrict__ dqw,
                                               u16* __restrict__ dpw) {
  const int N1 = 1310720;            // 4096*1280/4
  const int N2 = 1228800;            // 3840*1280/4
  const int N3 = 409600;             // 1280*1280/4
  for (int c = blockIdx.x * 256 + threadIdx.x; c < N1 + N2 + N3;
       c += gridDim.x * 256) {
    const float* s;
    u16* d;
    int i, oi;
    if (c < N1) { s = h; d = dh; i = c * 4; oi = i; }
    else if (c < N1 + N2) {
      s = qw; d = dqw; i = (c - N1) * 4;
      int row = i / 1280, col = i - row * 1280;
      int rp = row;
      if (row < 2560) {                       // q,k regions: interleave (d, d+40)
        int dd = row % 80;
        int nd = (dd < 40) ? (2 * dd) : (2 * (dd - 40) + 1);
        rp = row - dd + nd;
      }
      oi = rp * 1280 + col;
    }
    else { s = pw; d = dpw; i = (c - N1 - N2) * 4; oi = i; }
    float4 v = *(const float4*)&s[i];
    u32 lo = (u32)f2bf(v.x) | ((u32)f2bf(v.y) << 16);
    u32 hi = (u32)f2bf(v.z) | ((u32)f2bf(v.w) << 16);
    uint2 o; o.x = lo; o.y = hi;
    *(uint2*)&d[oi] = o;
  }
}

// ======== QKV GEMM: 256^2 tile, 8-wave, ring-4 LDS, counted-vmcnt (R11 schedule) ========
// R15 epilogue: RoPE fused. Columns hold PERMUTED head dims (even nd = orig d,
// odd nd = orig d+40); pair lives at lane^1. Rotation: even: v*c - p*s; odd: v*c + p*s
// with angle rot[token*40 + (nd>>1)]. Bias fetched at inverse-permuted index.
__global__ __launch_bounds__(512, 2) void gemm_qkv(const u16* __restrict__ A,
                                                   const u16* __restrict__ B,
                                                   const float* __restrict__ bias,
                                                   const float* __restrict__ rot,
                                                   u16* __restrict__ qbuf,
                                                   u16* __restrict__ kc,
                                                   u16* __restrict__ vtb,
                                                   int M, int N, int K) {
  __shared__ u16 lds_[65536];              // A ring [4][256][32] | B ring [4][256][32]
  u16* ringA = lds_;
  u16* ringB = lds_ + 32768;
  const int tid = threadIdx.x, lane = tid & 63, w = tid >> 6;
  const int lr = lane & 15, lq = lane >> 4;
  const int wm = w >> 2, wn = w & 3;
  const int nwg = gridDim.x;
  const int per = nwg >> 3;
  const int flat = blockIdx.x;
  const int f2 = (flat & 7) * per + (flat >> 3);
  const int nbn = N >> 8;
  const int m0 = (f2 / nbn) << 8, n0 = (f2 % nbn) << 8;
  const int NT = K >> 5;

#define STAGE_M(t_, ring_, src0_)                                          \
  do {                                                                     \
    int tt = (t_);                                                         \
    u16* dst = (ring_) + (tt & 3) * 8192 + w * 512;                        \
    const u16* src = (src0_) + tt * 32;                                    \
    _Pragma("unroll") for (int l = 0; l < 2; ++l) {                        \
      int q = l * 512 + tid;                                               \
      int row = q >> 2, sl = (q & 3) ^ ((row >> 1) & 3);                   \
      gld_lds16(&src[(size_t)row * K + sl * 8], dst + l * 4096);           \
    }                                                                      \
  } while (0)

  const u16* A0 = A + (size_t)m0 * K;
  const u16* B0 = B + (size_t)n0 * K;

  f32x4 acc[8][4] = {};

  STAGE_M(0, ringA, A0); STAGE_M(0, ringB, B0);
  if (NT > 1) { STAGE_M(1, ringA, A0); STAGE_M(1, ringB, B0); }
  if (NT > 2) { STAGE_M(2, ringA, A0); STAGE_M(2, ringB, B0); }
  if (NT > 2) asm volatile("s_waitcnt vmcnt(8)" ::: "memory");
  else        asm volatile("s_waitcnt vmcnt(0)" ::: "memory");
  __builtin_amdgcn_s_barrier();
  __builtin_amdgcn_sched_barrier(0);

  short8v af[8], bf[4];
  for (int t = 0; t < NT; ++t) {
    const u16* As = ringA + (t & 3) * 8192;
    const u16* Bs = ringB + (t & 3) * 8192;
#pragma unroll
    for (int j = 0; j < 4; ++j) {
      int row = wn * 64 + j * 16 + lr;
      bf[j] = *(const short8v*)&Bs[row * 32 + ((lq ^ ((row >> 1) & 3)) << 3)];
    }
#pragma unroll
    for (int i = 0; i < 8; ++i) {
      int row = wm * 128 + i * 16 + lr;
      af[i] = *(const short8v*)&As[row * 32 + ((lq ^ ((row >> 1) & 3)) << 3)];
    }
    if (t + 3 < NT) { STAGE_M(t + 3, ringA, A0); STAGE_M(t + 3, ringB, B0); }
    __builtin_amdgcn_sched_barrier(0);
    {
      int rem = NT - t - 2;   // tiles allowed in flight after this wait
      if (rem >= 2)      asm volatile("s_waitcnt vmcnt(8)" ::: "memory");
      else if (rem == 1) asm volatile("s_waitcnt vmcnt(4)" ::: "memory");
      else               asm volatile("s_waitcnt vmcnt(0)" ::: "memory");
    }
    __builtin_amdgcn_s_barrier();
    __builtin_amdgcn_sched_barrier(0);
    __builtin_amdgcn_s_setprio(1);
#pragma unroll
    for (int i = 0; i < 8; ++i) {
      acc[i][0] = MFMA16x16x32(af[i], bf[0], acc[i][0]);
      acc[i][1] = MFMA16x16x32(af[i], bf[1], acc[i][1]);
      acc[i][2] = MFMA16x16x32(af[i], bf[2], acc[i][2]);
      acc[i][3] = MFMA16x16x32(af[i], bf[3], acc[i][3]);
    }
    __builtin_amdgcn_s_setprio(0);
  }
#undef STAGE_M

  // ---- split epilogue with fused RoPE: q (rotated+prescaled) / k (rotated, kc layout)
  // ---- / v (transposed). gn parity == lane parity; pair value lives at lane^1.
#pragma unroll
  for (int j = 0; j < 4; ++j) {
    int gn = n0 + wn * 64 + j * 16 + lr;
    if (gn < 1280) {
      int nd = gn % 80, dpr = nd >> 1, odd = nd & 1;
      float bv = bias[(gn - nd) + (odd ? 40 + dpr : dpr)];
#pragma unroll
      for (int i = 0; i < 8; ++i)
#pragma unroll
        for (int r = 0; r < 4; ++r) {
          int gm = m0 + wm * 128 + i * 16 + lq * 4 + r;
          float v = acc[i][j][r] + bv;
          float p = __shfl_xor(v, 1);
          float s_, c_;
          __sincosf(rot[gm * 40 + dpr], &s_, &c_);
          float o = odd ? (v * c_ + p * s_) : (v * c_ - p * s_);
          qbuf[(size_t)gm * 1280 + gn] = f2bf(o * SL2E);
        }
    } else if (gn < 2560) {
      int wi = gn - 1280, h = wi / 80, nd = wi % 80;
      int dpr = nd >> 1, odd = nd & 1;
      float bv = bias[1280 + h * 80 + (odd ? 40 + dpr : dpr)];
      u16* base = kc + ((size_t)(h * 10 + (nd >> 3)) * 4096) * 8 + (nd & 7);
#pragma unroll
      for (int i = 0; i < 8; ++i)
#pragma unroll
        for (int r = 0; r < 4; ++r) {
          int gm = m0 + wm * 128 + i * 16 + lq * 4 + r;
          float v = acc[i][j][r] + bv;
          float p = __shfl_xor(v, 1);
          float s_, c_;
          __sincosf(rot[gm * 40 + dpr], &s_, &c_);
          float o = odd ? (v * c_ + p * s_) : (v * c_ - p * s_);
          base[(size_t)gm * 8] = f2bf(o);
        }
    } else {
      int wi = gn - 2560, h = wi / 80, d = wi % 80;
      float bv = bias[gn];
      u16* vrow = vtb + (size_t)(h * 80 + d) * 4096;
#pragma unroll
      for (int i = 0; i < 8; ++i) {
        int gm0 = m0 + wm * 128 + i * 16 + lq * 4;
        alignas(8) u16 t4[4];
#pragma unroll
        for (int r = 0; r < 4; ++r) t4[r] = f2bf(acc[i][j][r] + bv);
        *(uint2*)&vrow[gm0] = *(const uint2*)t4;
      }
    }
  }
}

// ======== proj GEMM: 128^2 tile, 4 waves, ring-4 counted-vmcnt ========
__global__ __launch_bounds__(256) void gemm4r(const u16* __restrict__ A,
                                              const u16* __restrict__ B,
                                              const float* __restrict__ bias,
                                              float* __restrict__ Cout,
                                              int M, int N, int K) {
  __shared__ u16 lds_[32768];              // A ring [4][128][32] | B ring [4][128][32]
  u16* ringA = lds_;
  u16* ringB = lds_ + 16384;
  const int tid = threadIdx.x, lane = tid & 63, w = tid >> 6;
  const int lr = lane & 15, lq = lane >> 4;
  const int wr = w >> 1, wc = w & 1;
  const int nwg = gridDim.x;
  const int per = nwg >> 3;
  const int flat = blockIdx.x;
  const int f2 = (flat & 7) * per + (flat >> 3);
  const int nbn = N >> 7;
  const int m0 = (f2 / nbn) << 7, n0 = (f2 % nbn) << 7;
  const int NT = K >> 5;

#define STAGE_P(t_, ring_, src0_)                                          \
  do {                                                                     \
    int tt = (t_);                                                         \
    u16* dst = (ring_) + (tt & 3) * 4096 + w * 512;                        \
    const u16* src = (src0_) + tt * 32;                                    \
    _Pragma("unroll") for (int l = 0; l < 2; ++l) {                        \
      int q = l * 256 + tid;                                               \
      int row = q >> 2, sl = (q & 3) ^ ((row >> 1) & 3);                   \
      gld_lds16(&src[(size_t)row * K + sl * 8], dst + l * 2048);           \
    }                                                                      \
  } while (0)

  const u16* A0 = A + (size_t)m0 * K;
  const u16* B0 = B + (size_t)n0 * K;

  f32x4 acc[4][4] = {};

  STAGE_P(0, ringA, A0); STAGE_P(0, ringB, B0);
  if (NT > 1) { STAGE_P(1, ringA, A0); STAGE_P(1, ringB, B0); }
  if (NT > 2) { STAGE_P(2, ringA, A0); STAGE_P(2, ringB, B0); }
  if (NT > 2) asm volatile("s_waitcnt vmcnt(8)" ::: "memory");
  else        asm volatile("s_waitcnt vmcnt(0)" ::: "memory");
  __builtin_amdgcn_s_barrier();
  __builtin_amdgcn_sched_barrier(0);

  short8v af[4], bf[4];
  for (int t = 0; t < NT; ++t) {
    const u16* As = ringA + (t & 3) * 4096;
    const u16* Bs = ringB + (t & 3) * 4096;
#pragma unroll
    for (int i = 0; i < 4; ++i) {
      int row = wr * 64 + i * 16 + lr;
      af[i] = *(const short8v*)&As[row * 32 + ((lq ^ ((row >> 1) & 3)) << 3)];
    }
#pragma unroll
    for (int j = 0; j < 4; ++j) {
      int row = wc * 64 + j * 16 + lr;
      bf[j] = *(const short8v*)&Bs[row * 32 + ((lq ^ ((row >> 1) & 3)) << 3)];
    }
    if (t + 3 < NT) { STAGE_P(t + 3, ringA, A0); STAGE_P(t + 3, ringB, B0); }
    __builtin_amdgcn_sched_barrier(0);
    {
      int rem = NT - t - 2;
      if (rem >= 2)      asm volatile("s_waitcnt vmcnt(8)" ::: "memory");
      else if (rem == 1) asm volatile("s_waitcnt vmcnt(4)" ::: "memory");
      else               asm volatile("s_waitcnt vmcnt(0)" ::: "memory");
    }
    __builtin_amdgcn_s_barrier();
    __builtin_amdgcn_sched_barrier(0);
    __builtin_amdgcn_s_setprio(1);
#pragma unroll
    for (int i = 0; i < 4; ++i)
#pragma unroll
      for (int j = 0; j < 4; ++j)
        acc[i][j] = MFMA16x16x32(af[i], bf[j], acc[i][j]);
    __builtin_amdgcn_s_setprio(0);
  }
#undef STAGE_P

#pragma unroll
  for (int j = 0; j < 4; ++j) {
    int gn = n0 + wc * 64 + j * 16 + lr;
    float bv = bias[gn];
#pragma unroll
    for (int i = 0; i < 4; ++i) {
#pragma unroll
      for (int r = 0; r < 4; ++r) {
        int gm = m0 + wr * 64 + i * 16 + lq * 4 + r;
        Cout[(size_t)gm * N + gn] = acc[i][j][r] + bv;
      }
    }
  }
}

// ---------------- flash attention: 8 waves share each staged tile (256 q/block) ----------------
// grid (4,16,4) XCD-swizzled = 256 blocks, 512 thr; LDS 67.6KB -> 2 blocks/CU = 4 waves/SIMD.
// Head dims arrive PERMUTED (consistently for Q and K) -> QK^T unchanged; V untouched.
__global__ __launch_bounds__(512, 2) void attn_k(const u16* __restrict__ qbuf,
                                                 const u16* __restrict__ kc,
                                                 const u16* __restrict__ vtb,
                                                 u16* __restrict__ out,
                                                 const int* __restrict__ cu) {
  __shared__ u16 Kb[3][5120];    // [buf][dc 10][tok 64][8]
  __shared__ u16 Vb[3][6144];    // [buf][d 96][tokchunk 8][8]; row 80 = ones, 81..95 = 0
  const int tid = threadIdx.x, lane = tid & 63, w = tid >> 6;
  const int l31 = lane & 31, lh = lane >> 5;
  int flat = blockIdx.x + 4 * (blockIdx.y + 16 * blockIdx.z);
  int f2 = (flat & 7) * 32 + (flat >> 3);
  const int qt = f2 & 3, head = (f2 >> 2) & 15, seg = f2 >> 6;
  const int seg0 = cu[seg], qend = cu[seg + 1];
  const int q0 = seg0 + qt * 256;
  if (q0 >= qend) return;
  const int nkt = (qend - seg0 + 63) >> 6;

  // preset V pad rows 80..95 (row 80 = 1.0 for free rowsum), all 3 buffers
  for (int c = tid; c < 3072; c += 512) {
    int b = c >> 10, rc = c & 1023;
    Vb[b][5120 + rc] = (rc < 64) ? (u16)0x3F80 : (u16)0;
  }

  // ---- Q B-frags direct from qbuf (once; Q prescaled by SL2E) ----
  const int qtok = q0 + w * 32 + l31;
  const int qtokc = min(qtok, qend - 1);
  const u16* qb = qbuf + (size_t)qtokc * 1280 + head * 80 + lh * 8;
  short8v aq[5];
#pragma unroll
  for (int st = 0; st < 5; ++st) aq[st] = *(const short8v*)&qb[st * 16];

  const u16* kch = kc + (size_t)head * 10 * 4096 * 8;
  const u16* vth = vtb + (size_t)head * 80 * 4096;
  const int vrow = lane >> 3, vtc = (lane & 7) ^ (lane >> 3);

#define GLDK(i_, kb0_, buf_)                                                     \
  gld_lds16(&kch[((size_t)(i_) * 4096 + min((kb0_) + lane, 4095)) * 8],          \
            &Kb[buf_][(i_) * 512])
#define GLDV(i_, kb0_, buf_)                                                     \
  gld_lds16(&vth[(size_t)((i_) * 8 + vrow) * 4096 + min((kb0_) + vtc * 8, 4088)],\
            &Vb[buf_][(i_) * 512])
// waves 0-3: K{w, w+4} + (w<2 ? K{8+w} : V{6+w -> 8,9}); waves 4-7: V{w-4, w}
#define STAGE_KV(kt_, buf_)                                                      \
  do {                                                                           \
    int kb0_ = seg0 + (kt_) * 64;                                                \
    if (w < 4) {                                                                 \
      GLDK(w, kb0_, buf_);                                                       \
      GLDK(w + 4, kb0_, buf_);                                                   \
      if (w < 2) GLDK(8 + w, kb0_, buf_);                                        \
      else       GLDV(6 + w, kb0_, buf_);                                        \
    } else {                                                                     \
      GLDV(w - 4, kb0_, buf_);                                                   \
      GLDV(w, kb0_, buf_);                                                       \
    }                                                                            \
  } while (0)

  STAGE_KV(0, 0);
  if (nkt > 1) STAGE_KV(1, 1);
  __syncthreads();               // pad-init ds_writes visible to all waves

  f32x16 o_acc[3] = {};
  int cur = 0;
  for (int kt = 0; kt < nkt; ++kt) {
    const int valid = min(64, qend - (seg0 + kt * 64));
    if (kt + 1 < nkt) {
      if (w < 4) asm volatile("s_waitcnt vmcnt(3)" ::: "memory");
      else       asm volatile("s_waitcnt vmcnt(2)" ::: "memory");
    } else {
      asm volatile("s_waitcnt vmcnt(0)" ::: "memory");
    }
    __builtin_amdgcn_s_barrier();
    if (kt + 2 < nkt) {
      int ns = cur + 2; if (ns >= 3) ns -= 3;
      STAGE_KV(kt + 2, ns);
    }

    // ---- QK^T swapped: S^T[k][q] (Q prescaled -> p = exp2(sac)) ----
    f32x16 sac0 = {}, sac1 = {};
    const u16* kbp = &Kb[cur][l31 * 8];
    __builtin_amdgcn_s_setprio(1);
#pragma unroll
    for (int st = 0; st < 5; ++st) {
      int dc = st * 2 + lh;
      short8v kf0 = *(const short8v*)&kbp[dc * 512];
      short8v kf1 = *(const short8v*)&kbp[dc * 512 + 256];
      sac0 = MFMA32(kf0, aq[st], sac0);
      sac1 = MFMA32(kf1, aq[st], sac1);
    }
    __builtin_amdgcn_s_setprio(0);

    f32x16 p0, p1;
#pragma unroll
    for (int i = 0; i < 16; ++i) {
      p0[i] = exp2f(sac0[i]);
      p1[i] = exp2f(sac1[i]);
    }
    if (valid < 64) {
#pragma unroll
      for (int i = 0; i < 16; ++i) {
        int k0_ = (i & 3) + 8 * (i >> 2) + 4 * lh;
        if (k0_ >= valid) p0[i] = 0.f;
        if (32 + k0_ >= valid) p1[i] = 0.f;
      }
    }

    // ---- P -> PV B-frags via cvt_pk + permlane32_swap (no LDS) ----
    short8v pfrag[4];
#pragma unroll
    for (int st = 0; st < 4; ++st) {
      int s0 = 8 * (st & 1);
      u32 c0, c1, c2, c3;
      if (st < 2) {
        asm("v_cvt_pk_bf16_f32 %0, %1, %2" : "=v"(c0) : "v"(p0[s0 + 0]), "v"(p0[s0 + 1]));
        asm("v_cvt_pk_bf16_f32 %0, %1, %2" : "=v"(c1) : "v"(p0[s0 + 2]), "v"(p0[s0 + 3]));
        asm("v_cvt_pk_bf16_f32 %0, %1, %2" : "=v"(c2) : "v"(p0[s0 + 4]), "v"(p0[s0 + 5]));
        asm("v_cvt_pk_bf16_f32 %0, %1, %2" : "=v"(c3) : "v"(p0[s0 + 6]), "v"(p0[s0 + 7]));
      } else {
        asm("v_cvt_pk_bf16_f32 %0, %1, %2" : "=v"(c0) : "v"(p1[s0 + 0]), "v"(p1[s0 + 1]));
        asm("v_cvt_pk_bf16_f32 %0, %1, %2" : "=v"(c1) : "v"(p1[s0 + 2]), "v"(p1[s0 + 3]));
        asm("v_cvt_pk_bf16_f32 %0, %1, %2" : "=v"(c2) : "v"(p1[s0 + 4]), "v"(p1[s0 + 5]));
        asm("v_cvt_pk_bf16_f32 %0, %1, %2" : "=v"(c3) : "v"(p1[s0 + 6]), "v"(p1[s0 + 7]));
      }
      asm volatile("v_permlane32_swap_b32 %0, %1" : "+v"(c0), "+v"(c2));
      asm volatile("v_permlane32_swap_b32 %0, %1" : "+v"(c1), "+v"(c3));
      uint4 u = make_uint4(c0, c1, c2, c3);
      pfrag[st] = *reinterpret_cast<short8v*>(&u);
    }

    // ---- PV: O^T[d][q] += V * P (row 80 of V = ones -> rowsum in o_acc[2][8], lh=0) ----
    __builtin_amdgcn_s_setprio(1);
#pragma unroll
    for (int df = 0; df < 3; ++df) {
#pragma unroll
      for (int st2 = 0; st2 < 4; ++st2) {
        int tcp = (st2 * 2 + lh) ^ (l31 & 7);
        short8v vf = *(const short8v*)&Vb[cur][(df * 32 + l31) * 64 + tcp * 8];
        o_acc[df] = MFMA32(vf, pfrag[st2], o_acc[df]);
      }
    }
    __builtin_amdgcn_s_setprio(0);

    cur = (cur == 2) ? 0 : cur + 1;
  }
#undef STAGE_KV
#undef GLDK
#undef GLDV

  // ---- normalize + store (lh=1 partner's o_acc[2][8] is V-row 84 = 0, so sum is safe) ----
  float rs = o_acc[2][8];
  rs += __shfl_xor(rs, 32);
  float invq = 1.0f / rs;
  if (qtok < qend) {
#pragma unroll
    for (int df = 0; df < 3; ++df) {
#pragma unroll
      for (int i = 0; i < 16; ++i) {
        if (df == 2 && i >= 8) continue;
        int d = df * 32 + (i & 3) + 8 * (i >> 2) + 4 * lh;
        out[(size_t)qtok * 1280 + head * 80 + d] = f2bf(o_acc[df][i] * invq);
      }
    }
  }
}

// ---------------- host launch ----------------
extern "C" void kernel_launch(void* const* d_in, const int* in_sizes, int n_in,
                              void* d_out, int out_size, void* d_ws, size_t ws_size,
                              hipStream_t stream) {
  const float* hidden = (const float*)d_in[0];
  const float* rot    = (const float*)d_in[1];
  const float* qkv_w  = (const float*)d_in[2];
  const float* qkv_b  = (const float*)d_in[3];
  const float* proj_w = (const float*)d_in[4];
  const float* proj_b = (const float*)d_in[5];
  const int*   cu     = (const int*)d_in[6];
  float* out = (float*)d_out;

  char* ws = (char*)d_ws;
  u16* hid_bf   = (u16*)(ws);                    // 10,485,760
  u16* qkvw_bf  = (u16*)(ws + 10485760);         //  9,830,400
  u16* projw_bf = (u16*)(ws + 20316160);         //  3,276,800
  u16* qbuf     = (u16*)(ws + 23592960);         // 10,485,760
  u16* kc       = (u16*)(ws + 34078720);         // 10,485,760
  u16* vtb      = (u16*)(ws + 44564480);         // 10,485,760
  u16* attn_bf  = (u16*)(ws + 55050240);         // 10,485,760 -> total 65,536,000

  cvt_all<<<2048, 256, 0, stream>>>(hidden, qkv_w, proj_w, hid_bf, qkvw_bf, projw_bf);

  gemm_qkv<<<240, 512, 0, stream>>>(hid_bf, qkvw_bf, qkv_b, rot, qbuf, kc, vtb,
                                    4096, 3840, 1280);
  attn_k<<<dim3(4, 16, 4), 512, 0, stream>>>(qbuf, kc, vtb, attn_bf, cu);
  gemm4r<<<320, 256, 0, stream>>>(attn_bf, projw_bf, proj_b, out, 4096, 1280, 1280);
}